// Round 3
// baseline (521.398 us; speedup 1.0000x reference)
//
#include <hip/hip_runtime.h>
#include <hip/hip_cooperative_groups.h>
#include <math.h>

namespace cg = cooperative_groups;

#define N_NODES 100000
#define N_EDGES 1000000
#define NB 8
#define NBUCK 256              // buckets per role == grid size == chunks
#define BROWS 392              // rows per bucket; 256*392 = 100352 >= N
#define CAP 6144               // per-bucket capacity (expected ~3906 +- 6sigma)
#define CHUNKC 3907            // ceil(N_EDGES / 256)
#define ITER 8                 // ceil(CHUNKC / 512)

// ws layout:
// cursors[512*16] int   (row cursors [0..256), col cursors [256..512); 1 live int / 64B)
// cntT[256*8] float     (per-bucket batch-count partials)
// partial[256*512] float
// Y[512] float
// db[N] uint2           {dinv_bits, batch}
// rowBin[256*CAP] uint2 {(c<<9)|(r%392), ew_bits}
// colBin[256*CAP] uint2 {c%392, ew_bits}

union __align__(16) SM {
    struct {                                    // phase 1: dual counting sort
        uint2 sPay[CHUNKC];                     // 31256 B
        int hist[2 * NBUCK], scan[2 * NBUCK];
        int gbase[2 * NBUCK], off[2 * NBUCK];   // 8192 B
        unsigned char sBkt[CHUNKC];             // 3907 B
    } c;
    struct { float degsub[BROWS]; float cb[NB]; } d;        // phase 2
    struct { float Ssub[BROWS * NB]; float red[512]; } b;   // phases 3,4
    struct {                                    // phase 5 (tail)
        float Ws[64 * 64];                      // 16 KB
        float lWs[128 * 64];                    // 32 KB
        float Ys[512], Hs[512], P[512], Gz[512];
        float cnt_s[NB];
    } e;
};

__global__ __launch_bounds__(512) void kFused(
        const float* __restrict__ X, const int* __restrict__ row,
        const int* __restrict__ col, const float* __restrict__ ew,
        const int* __restrict__ batch, const float* __restrict__ H,
        const float* __restrict__ Wz, const float* __restrict__ bz,
        const float* __restrict__ lzW, const float* __restrict__ lzb,
        const float* __restrict__ Wh, const float* __restrict__ bh,
        const float* __restrict__ lhW, const float* __restrict__ lhb,
        float* __restrict__ out,
        int* __restrict__ cursors, float* __restrict__ cntT,
        float* __restrict__ partial, float* __restrict__ Y,
        uint2* __restrict__ db, uint2* __restrict__ rowBin,
        uint2* __restrict__ colBin) {
    cg::grid_group grid = cg::this_grid();
    __shared__ SM sm;
    const int tid = threadIdx.x;
    const int bid = blockIdx.x;

    // ---- P0: cursor init; atomicExch lands at the coherence point so other
    // XCDs' atomicAdds see it without relying on plain-store flush ----
    if (tid < 2) atomicExch(&cursors[(tid * NBUCK + bid) * 16], bid * CAP);
    __threadfence();
    grid.sync();
    __threadfence();

    // ---- P1: chunk bid -> dual LDS counting sort -> coalesced bin runs ----
    {
        const int beg = bid * CHUNKC;
        const int end = min(N_EDGES, beg + CHUNKC);
        const int T   = end - beg;

        sm.c.hist[tid] = 0;
        __syncthreads();

        int rx[ITER], cx[ITER]; float wv[ITER];
        #pragma unroll
        for (int it = 0; it < ITER; ++it) {
            const int i = beg + it * 512 + tid;
            if (i < end) {
                rx[it] = row[i]; cx[it] = col[i]; wv[it] = ew[i];
                atomicAdd(&sm.c.hist[rx[it] / BROWS], 1);
                atomicAdd(&sm.c.hist[NBUCK + cx[it] / BROWS], 1);
            } else rx[it] = -1;
        }
        __syncthreads();

        // two independent inclusive scans (row half / col half)
        sm.c.scan[tid] = sm.c.hist[tid];
        __syncthreads();
        for (int s = 1; s < NBUCK; s <<= 1) {
            const int l = tid & (NBUCK - 1);
            int v = 0;
            if (l >= s) v = sm.c.scan[tid - s];
            __syncthreads();
            if (l >= s) sm.c.scan[tid] += v;
            __syncthreads();
        }

        {
            const int eb = sm.c.scan[tid] - sm.c.hist[tid];
            sm.c.gbase[tid] = atomicAdd(&cursors[tid * 16], sm.c.hist[tid]);
            sm.c.scan[tid] = eb;
            sm.c.off[tid] = eb;
        }
        __syncthreads();

        // row-binned payloads {(c<<9)|rl, ew}
        #pragma unroll
        for (int it = 0; it < ITER; ++it) {
            if (rx[it] >= 0) {
                const int kb = rx[it] / BROWS;
                const int xl = rx[it] - kb * BROWS;    // < 392, fits 9 bits
                const int p = atomicAdd(&sm.c.off[kb], 1);
                sm.c.sPay[p] = make_uint2((unsigned)((cx[it] << 9) | xl),
                                          __float_as_uint(wv[it]));
                sm.c.sBkt[p] = (unsigned char)kb;
            }
        }
        __syncthreads();
        for (int j = tid; j < T; j += 512) {
            const int b2 = sm.c.sBkt[j];
            const int dst = sm.c.gbase[b2] + (j - sm.c.scan[b2]);
            if (dst < (b2 + 1) * CAP) rowBin[dst] = sm.c.sPay[j];
        }
        __syncthreads();

        // col-binned payloads {cl, ew} (sPay reused)
        #pragma unroll
        for (int it = 0; it < ITER; ++it) {
            if (rx[it] >= 0) {
                const int kb = cx[it] / BROWS;
                const int xl = cx[it] - kb * BROWS;
                const int p = atomicAdd(&sm.c.off[NBUCK + kb], 1);
                sm.c.sPay[p] = make_uint2((unsigned)xl, __float_as_uint(wv[it]));
                sm.c.sBkt[p] = (unsigned char)kb;
            }
        }
        __syncthreads();
        for (int j = tid; j < T; j += 512) {
            const int b2 = sm.c.sBkt[j];
            const int dst = sm.c.gbase[NBUCK + b2] + (j - sm.c.scan[NBUCK + b2]);
            if (dst < (b2 + 1) * CAP) colBin[dst] = sm.c.sPay[j];
        }
    }
    __threadfence();
    grid.sync();
    __threadfence();

    // ---- P2: col-bucket bid -> deg -> {dinv, batch}; batch-count partials ----
    {
        if (tid < BROWS) sm.d.degsub[tid] = 0.f;
        if (tid < NB) sm.d.cb[tid] = 0.f;
        __syncthreads();
        const int beg = bid * CAP;
        const int end2 = min(cursors[(NBUCK + bid) * 16], beg + CAP);
        for (int i = beg + tid; i < end2; i += 512) {
            const uint2 v = colBin[i];
            atomicAdd(&sm.d.degsub[v.x], __uint_as_float(v.y));
        }
        __syncthreads();
        if (tid < BROWS) {
            const int r = bid * BROWS + tid;
            if (r < N_NODES) {
                const float dv = rsqrtf(sm.d.degsub[tid] + 1.0f);   // + self-loop
                const int gg = batch[r];
                db[r] = make_uint2(__float_as_uint(dv), (unsigned)gg);
                atomicAdd(&sm.d.cb[gg], 1.0f);
            }
        }
        __syncthreads();
        if (tid < NB) cntT[bid * NB + tid] = sm.d.cb[tid];
    }
    __threadfence();
    grid.sync();
    __threadfence();

    // ---- P3: row-bucket bid -> LDS S-subtile + fused partial-Y GEMV ----
    {
        const int r0 = bid * BROWS;
        for (int i = tid; i < BROWS * NB; i += 512) sm.b.Ssub[i] = 0.f;
        __syncthreads();

        const int beg = bid * CAP;
        const int end2 = min(cursors[bid * 16], beg + CAP);
        for (int i = beg + tid; i < end2; i += 512) {
            const uint2 v = rowBin[i];
            const uint2 d = db[v.x >> 9];                 // {dinv[c], batch[c]}
            atomicAdd(&sm.b.Ssub[((v.x & 511) << 3) | d.y],
                      __uint_as_float(d.x) * __uint_as_float(v.y));
        }
        if (tid < BROWS) {   // self-loop (dinv[r] applied at GEMV; /cnt at tail)
            const int r = r0 + tid;
            if (r < N_NODES) {
                const uint2 d = db[r];
                atomicAdd(&sm.b.Ssub[(tid << 3) | d.y], __uint_as_float(d.x));
            }
        }
        __syncthreads();

        const int k4  = tid & 15;
        const int rid = tid >> 4;          // 32 rows in flight
        float acc[8][4];
        #pragma unroll
        for (int g = 0; g < 8; ++g)
            #pragma unroll
            for (int c = 0; c < 4; ++c) acc[g][c] = 0.f;

        for (int it = 0; it < (BROWS + 31) / 32; ++it) {
            const int lr = it * 32 + rid;
            const int r  = r0 + lr;
            if (lr < BROWS && r < N_NODES) {
                const float dv = __uint_as_float(db[r].x);
                const float4 x = *reinterpret_cast<const float4*>(X + (long)r * 64 + k4 * 4);
                float4 s0 = *reinterpret_cast<const float4*>(&sm.b.Ssub[lr * 8]);
                float4 s1 = *reinterpret_cast<const float4*>(&sm.b.Ssub[lr * 8 + 4]);
                const float sg[8] = {s0.x * dv, s0.y * dv, s0.z * dv, s0.w * dv,
                                     s1.x * dv, s1.y * dv, s1.z * dv, s1.w * dv};
                #pragma unroll
                for (int g = 0; g < 8; ++g) {
                    acc[g][0] += sg[g] * x.x;
                    acc[g][1] += sg[g] * x.y;
                    acc[g][2] += sg[g] * x.z;
                    acc[g][3] += sg[g] * x.w;
                }
            }
        }

        #pragma unroll
        for (int g = 0; g < 8; ++g)
            #pragma unroll
            for (int c = 0; c < 4; ++c) {
                float v = acc[g][c];
                v += __shfl_xor(v, 16);
                v += __shfl_xor(v, 32);
                acc[g][c] = v;
            }

        sm.b.red[tid] = 0.f;
        __syncthreads();
        if ((tid & 48) == 0) {
            #pragma unroll
            for (int g = 0; g < 8; ++g)
                #pragma unroll
                for (int c = 0; c < 4; ++c)
                    atomicAdd(&sm.b.red[g * 64 + k4 * 4 + c], acc[g][c]);
        }
        __syncthreads();
        partial[(long)bid * 512 + tid] = sm.b.red[tid];
    }
    __threadfence();
    grid.sync();
    __threadfence();

    // ---- P4: reduce partial over buckets; 2 outputs per block ----
    {
        const int half = tid >> 8;          // 0..1
        const int l    = tid & 255;         // bucket index
        const int t4   = 2 * bid + half;
        float s = partial[(long)l * 512 + t4];
        #pragma unroll
        for (int m = 1; m <= 32; m <<= 1) s += __shfl_xor(s, m);
        if ((tid & 63) == 0) sm.b.red[tid >> 6] = s;   // 8 wave partials
        __syncthreads();
        if (tid < 2) {
            const float* r4 = &sm.b.red[tid * 4];
            Y[2 * bid + tid] = r4[0] + r4[1] + r4[2] + r4[3];
        }
    }
    __threadfence();
    grid.sync();
    __threadfence();

    // ---- P5: tail on block 0 (cnt reduce + /cnt + z-gate + h-gate + combine) ----
    if (bid == 0) {
        const int t = tid;
        const int g = t >> 6, j = t & 63;

        {   // reduce cntT[256][8] -> cnt_s (P used as scratch)
            const int gg = t & 7, k = t >> 3;           // k in [0,64)
            float cv = 0.f;
            #pragma unroll
            for (int q = 0; q < 4; ++q) cv += cntT[(k + q * 64) * NB + gg];
            cv += __shfl_xor(cv, 8);
            cv += __shfl_xor(cv, 16);
            cv += __shfl_xor(cv, 32);
            if ((t & 63) < 8) sm.e.P[(t >> 6) * NB + gg] = cv;
        }
        const float yv = Y[t];
        sm.e.Hs[t] = H[t];
        {
            const float4* W4  = reinterpret_cast<const float4*>(Wz);
            const float4* lW4 = reinterpret_cast<const float4*>(lzW);
            float4* Ws4  = reinterpret_cast<float4*>(sm.e.Ws);
            float4* lWs4 = reinterpret_cast<float4*>(sm.e.lWs);
            #pragma unroll
            for (int i = 0; i < 2; ++i) Ws4[t + 512 * i] = W4[t + 512 * i];
            #pragma unroll
            for (int i = 0; i < 4; ++i) lWs4[t + 512 * i] = lW4[t + 512 * i];
        }
        __syncthreads();
        if (t < NB) {
            float s = 0.f;
            #pragma unroll
            for (int w = 0; w < 8; ++w) s += sm.e.P[w * NB + t];
            sm.e.cnt_s[t] = fmaxf(s, 1.0f);
        }
        __syncthreads();
        sm.e.Ys[t] = yv / sm.e.cnt_s[g];
        __syncthreads();

        float p = bz[j];
        #pragma unroll 8
        for (int k = 0; k < 64; ++k) p += sm.e.Ys[g * 64 + k] * sm.e.Ws[k * 64 + j];
        sm.e.P[t] = p;
        __syncthreads();
        float az = lzb[j];
        #pragma unroll 8
        for (int k = 0; k < 64; ++k)
            az += sm.e.P[g * 64 + k] * sm.e.lWs[k * 64 + j]
                + sm.e.Hs[g * 64 + k] * sm.e.lWs[(64 + k) * 64 + j];
        sm.e.Gz[t] = 1.f / (1.f + expf(-az));
        __syncthreads();

        {
            const float4* W4  = reinterpret_cast<const float4*>(Wh);
            const float4* lW4 = reinterpret_cast<const float4*>(lhW);
            float4* Ws4  = reinterpret_cast<float4*>(sm.e.Ws);
            float4* lWs4 = reinterpret_cast<float4*>(sm.e.lWs);
            #pragma unroll
            for (int i = 0; i < 2; ++i) Ws4[t + 512 * i] = W4[t + 512 * i];
            #pragma unroll
            for (int i = 0; i < 4; ++i) lWs4[t + 512 * i] = lW4[t + 512 * i];
        }
        __syncthreads();

        p = bh[j];
        #pragma unroll 8
        for (int k = 0; k < 64; ++k) p += sm.e.Ys[g * 64 + k] * sm.e.Ws[k * 64 + j];
        sm.e.P[t] = p;
        __syncthreads();
        float ah = lhb[j];
        #pragma unroll 8
        for (int k = 0; k < 64; ++k)
            ah += sm.e.P[g * 64 + k] * sm.e.lWs[k * 64 + j]
                + sm.e.Hs[g * 64 + k] * sm.e.lWs[(64 + k) * 64 + j];
        const float Ht = tanhf(ah);

        out[t] = sm.e.Gz[t] * sm.e.Hs[t] + (1.f - sm.e.Gz[t]) * Ht;
    }
}

extern "C" void kernel_launch(void* const* d_in, const int* in_sizes, int n_in,
                              void* d_out, int out_size, void* d_ws, size_t ws_size,
                              hipStream_t stream) {
    (void)in_sizes; (void)n_in; (void)out_size; (void)ws_size;

    const float* X     = (const float*)d_in[0];
    const int*   ei    = (const int*)d_in[1];
    const int*   rowp  = ei;
    const int*   colp  = ei + N_EDGES;
    const int*   batch = (const int*)d_in[2];
    const float* ew    = (const float*)d_in[3];
    const float* H     = (const float*)d_in[4];
    const float* Wz  = (const float*)d_in[5];
    const float* bz  = (const float*)d_in[6];
    const float* lzW = (const float*)d_in[7];
    const float* lzb = (const float*)d_in[8];
    // gate r (d_in[9..12]) computed-but-unused in the reference -> skipped
    const float* Wh  = (const float*)d_in[13];
    const float* bh  = (const float*)d_in[14];
    const float* lhW = (const float*)d_in[15];
    const float* lhb = (const float*)d_in[16];
    float* out = (float*)d_out;

    const long NCAP = (long)NBUCK * CAP;
    int*   cursors = (int*)d_ws;                           // 512*16 ints
    float* cntT    = (float*)(cursors + 2 * NBUCK * 16);   // 256*8
    float* partial = cntT + NBUCK * NB;                    // 256*512
    float* Yv      = partial + (long)NBUCK * 512;          // 512
    uint2* db      = (uint2*)(Yv + 512);                   // N * 8B
    uint2* rowBin  = db + N_NODES;                         // NCAP * 8B
    uint2* colBin  = rowBin + NCAP;                        // NCAP * 8B

    void* args[] = {
        (void*)&X, (void*)&rowp, (void*)&colp, (void*)&ew, (void*)&batch,
        (void*)&H, (void*)&Wz, (void*)&bz, (void*)&lzW, (void*)&lzb,
        (void*)&Wh, (void*)&bh, (void*)&lhW, (void*)&lhb, (void*)&out,
        (void*)&cursors, (void*)&cntT, (void*)&partial, (void*)&Yv,
        (void*)&db, (void*)&rowBin, (void*)&colBin};
    hipLaunchCooperativeKernel((void*)kFused, dim3(NBUCK), dim3(512),
                               args, 0, stream);
}

// Round 4
// 69.659 us; speedup vs baseline: 7.4850x; 7.4850x over previous
//
#include <hip/hip_runtime.h>
#include <math.h>

#define N_NODES 100000
#define N_EDGES 1000000
#define NB 8
#define NBUCK 256              // buckets per role; 512 cursors total
#define BROWS 392              // rows per bucket; 256*392 = 100352 >= N
#define CAP 6144               // per-bucket capacity (expected ~3906 +- 6sigma)
#define NCHUNK 512             // edge chunks
#define CHUNKC 1956            // ceil(1e6/512) rounded up to multiple of 4; 512*1956 >= 1e6
#define EPT 4                  // edges per thread (one int4/float4 per array)

// ws layout:
// cursors[512*16] int   (row cursors [0..256), col cursors [256..512); 1 live int / 64B)
// cntG[8] float         (per-graph node counts)
// partial[256*512] float
// Y[512] float
// db[N] uint2           {dinv_bits, batch}
// rowBin[256*CAP] uint2 {(c<<9)|(r%392), ew_bits}
// colBin[256*CAP] uint2 {c%392, ew_bits}

__global__ __launch_bounds__(512) void kInit(int* __restrict__ cursors,
        float* __restrict__ cntG) {
    const int t = threadIdx.x;
    const int b = (t < NBUCK) ? t : t - NBUCK;
    cursors[t * 16] = b * CAP;
    if (t < NB) cntG[t] = 0.f;
}

// Single pass over the edge list. Per 1956-edge chunk: int4 vector loads ->
// dual LDS histogram -> wave-level shfl scan (no block barriers) -> cursor
// reservation -> dual block-local counting sort (both payloads LDS-resident)
// -> interleaved coalesced run writes. 4 __syncthreads total; 2 blocks/CU.
__global__ __launch_bounds__(512) void kC(const int* __restrict__ row,
        const int* __restrict__ col, const float* __restrict__ ew,
        int* __restrict__ cursors, uint2* __restrict__ rowBin,
        uint2* __restrict__ colBin) {
    __shared__ uint2 sPayR[CHUNKC], sPayC[CHUNKC];          // 2 x 15648 B
    __shared__ int hist[2 * NBUCK], scan[2 * NBUCK];
    __shared__ int gbase[2 * NBUCK], off[2 * NBUCK];        // 8192 B
    __shared__ unsigned char sBktR[CHUNKC], sBktC[CHUNKC];  // 2 x 1956 B
    const int tid = threadIdx.x;
    const int beg = blockIdx.x * CHUNKC;
    const int end = min(N_EDGES, beg + CHUNKC);
    const int T   = end - beg;      // always a multiple of 4

    hist[tid] = 0;
    __syncthreads();

    // vector edge loads: thread t owns edges [beg+4t, beg+4t+4) — all or none
    const int e0 = beg + EPT * tid;
    const bool act = (e0 < end);
    int4 r4, c4; float4 w4;
    if (act) {
        r4 = *reinterpret_cast<const int4*>(row + e0);
        c4 = *reinterpret_cast<const int4*>(col + e0);
        w4 = *reinterpret_cast<const float4*>(ew + e0);
        atomicAdd(&hist[r4.x / BROWS], 1);
        atomicAdd(&hist[r4.y / BROWS], 1);
        atomicAdd(&hist[r4.z / BROWS], 1);
        atomicAdd(&hist[r4.w / BROWS], 1);
        atomicAdd(&hist[NBUCK + c4.x / BROWS], 1);
        atomicAdd(&hist[NBUCK + c4.y / BROWS], 1);
        atomicAdd(&hist[NBUCK + c4.z / BROWS], 1);
        atomicAdd(&hist[NBUCK + c4.w / BROWS], 1);
    }
    __syncthreads();

    // wave 0 scans the row half, wave 1 the col half: lane handles 4 buckets,
    // shfl-based inclusive scan of lane totals (no block barriers)
    const int wave = tid >> 6, lane = tid & 63;
    if (wave < 2) {
        const int b0 = wave * NBUCK + lane * 4;
        const int h0 = hist[b0], h1 = hist[b0 + 1];
        const int h2 = hist[b0 + 2], h3 = hist[b0 + 3];
        const int t01 = h0 + h1;
        const int tot = t01 + h2 + h3;
        int inc = tot;
        #pragma unroll
        for (int d = 1; d < 64; d <<= 1) {
            const int v = __shfl_up(inc, d);
            if (lane >= d) inc += v;
        }
        const int excl = inc - tot;
        scan[b0]     = excl;            off[b0]     = excl;
        scan[b0 + 1] = excl + h0;       off[b0 + 1] = excl + h0;
        scan[b0 + 2] = excl + t01;      off[b0 + 2] = excl + t01;
        scan[b0 + 3] = excl + t01 + h2; off[b0 + 3] = excl + t01 + h2;
        gbase[b0]     = atomicAdd(&cursors[(b0)     * 16], h0);
        gbase[b0 + 1] = atomicAdd(&cursors[(b0 + 1) * 16], h1);
        gbase[b0 + 2] = atomicAdd(&cursors[(b0 + 2) * 16], h2);
        gbase[b0 + 3] = atomicAdd(&cursors[(b0 + 3) * 16], h3);
    }
    __syncthreads();

    // dual scatter into LDS (both roles in one pass)
    if (act) {
        #pragma unroll
        for (int j = 0; j < EPT; ++j) {
            const int rv = (&r4.x)[j];
            const int cv = (&c4.x)[j];
            const unsigned wb = __float_as_uint((&w4.x)[j]);
            const int rb = rv / BROWS, rl = rv - rb * BROWS;   // rl < 392, 9 bits
            const int p = atomicAdd(&off[rb], 1);
            sPayR[p] = make_uint2((unsigned)((cv << 9) | rl), wb);
            sBktR[p] = (unsigned char)rb;
            const int cb = cv / BROWS, cl = cv - cb * BROWS;
            const int q = atomicAdd(&off[NBUCK + cb], 1);
            sPayC[q] = make_uint2((unsigned)cl, wb);
            sBktC[q] = (unsigned char)cb;
        }
    }
    __syncthreads();

    // interleaved coalesced run write-out (two independent store streams)
    for (int j = tid; j < T; j += 512) {
        {
            const int b = sBktR[j];
            const int dst = gbase[b] + (j - scan[b]);
            if (dst < (b + 1) * CAP) rowBin[dst] = sPayR[j];
        }
        {
            const int b = sBktC[j];
            const int dst = gbase[NBUCK + b] + (j - scan[NBUCK + b]);
            if (dst < (b + 1) * CAP) colBin[dst] = sPayC[j];
        }
    }
}

// per col-bucket: LDS deg accumulation -> packed {dinv, batch}; per-graph counts
__global__ __launch_bounds__(512) void kD_degacc(const uint2* __restrict__ colBin,
        const int* __restrict__ cursors, const int* __restrict__ batch,
        uint2* __restrict__ db, float* __restrict__ cntG) {
    __shared__ float degsub[BROWS];
    __shared__ float cb[NB];
    const int tid = threadIdx.x;
    const int kb  = blockIdx.x;
    if (tid < BROWS) degsub[tid] = 0.f;
    if (tid < NB) cb[tid] = 0.f;
    __syncthreads();
    const int beg = kb * CAP;
    const int end = min(cursors[(NBUCK + kb) * 16], beg + CAP);
    for (int i = beg + tid; i < end; i += 512) {
        const uint2 v = colBin[i];
        atomicAdd(&degsub[v.x], __uint_as_float(v.y));
    }
    __syncthreads();
    if (tid < BROWS) {
        const int r = kb * BROWS + tid;
        if (r < N_NODES) {
            const float dv = rsqrtf(degsub[tid] + 1.0f);   // + self-loop weight
            const int g = batch[r];
            db[r] = make_uint2(__float_as_uint(dv), (unsigned)g);
            atomicAdd(&cb[g], 1.0f);
        }
    }
    __syncthreads();
    if (tid < NB) atomicAdd(&cntG[tid], cb[tid]);
}

// per row-bucket: LDS S-subtile accumulation (dinv[r] deferred) + fused partial-Y GEMV
__global__ __launch_bounds__(512) void kD_bucket(const float* __restrict__ X,
        const uint2* __restrict__ rowBin, const int* __restrict__ cursors,
        const uint2* __restrict__ db, float* __restrict__ partial) {
    __shared__ float Ssub[BROWS * NB];   // 12.5 KB
    __shared__ float red[512];
    const int tid = threadIdx.x;
    const int kb  = blockIdx.x;
    const int r0  = kb * BROWS;

    for (int i = tid; i < BROWS * NB; i += 512) Ssub[i] = 0.f;
    __syncthreads();

    const int beg = kb * CAP;
    const int end = min(cursors[kb * 16], beg + CAP);
    for (int i = beg + tid; i < end; i += 512) {
        const uint2 v = rowBin[i];
        const uint2 d = db[v.x >> 9];                 // {dinv[c], batch[c]}
        atomicAdd(&Ssub[((v.x & 511) << 3) | d.y],
                  __uint_as_float(d.x) * __uint_as_float(v.y));
    }
    if (tid < BROWS) {   // self-loop (dinv[r] applied at GEMV; /cnt at tail)
        const int r = r0 + tid;
        if (r < N_NODES) {
            const uint2 d = db[r];
            atomicAdd(&Ssub[(tid << 3) | d.y], __uint_as_float(d.x));
        }
    }
    __syncthreads();

    const int k4  = tid & 15;
    const int rid = tid >> 4;          // 32 rows in flight
    float acc[8][4];
    #pragma unroll
    for (int g = 0; g < 8; ++g)
        #pragma unroll
        for (int c = 0; c < 4; ++c) acc[g][c] = 0.f;

    for (int it = 0; it < (BROWS + 31) / 32; ++it) {
        const int lr = it * 32 + rid;
        const int r  = r0 + lr;
        if (lr < BROWS && r < N_NODES) {
            const float dv = __uint_as_float(db[r].x);
            const float4 x  = *reinterpret_cast<const float4*>(X + (long)r * 64 + k4 * 4);
            float4 s0 = *reinterpret_cast<const float4*>(&Ssub[lr * 8]);
            float4 s1 = *reinterpret_cast<const float4*>(&Ssub[lr * 8 + 4]);
            const float sg[8] = {s0.x * dv, s0.y * dv, s0.z * dv, s0.w * dv,
                                 s1.x * dv, s1.y * dv, s1.z * dv, s1.w * dv};
            #pragma unroll
            for (int g = 0; g < 8; ++g) {
                acc[g][0] += sg[g] * x.x;
                acc[g][1] += sg[g] * x.y;
                acc[g][2] += sg[g] * x.z;
                acc[g][3] += sg[g] * x.w;
            }
        }
    }

    #pragma unroll
    for (int g = 0; g < 8; ++g)
        #pragma unroll
        for (int c = 0; c < 4; ++c) {
            float v = acc[g][c];
            v += __shfl_xor(v, 16);
            v += __shfl_xor(v, 32);
            acc[g][c] = v;
        }

    red[tid] = 0.f;
    __syncthreads();
    if ((tid & 48) == 0) {
        #pragma unroll
        for (int g = 0; g < 8; ++g)
            #pragma unroll
            for (int c = 0; c < 4; ++c)
                atomicAdd(&red[g * 64 + k4 * 4 + c], acc[g][c]);
    }
    __syncthreads();
    partial[(long)kb * 512 + tid] = red[tid];
}

// 512 one-wave blocks: reduce partial -> Y[t]
__global__ __launch_bounds__(64) void k45_reduce(const float* __restrict__ partial,
        float* __restrict__ Y) {
    const int bid = blockIdx.x;
    const int lane = threadIdx.x;
    float s = 0.f;
    for (int b = lane; b < NBUCK; b += 64)
        s += partial[(long)b * 512 + bid];
    #pragma unroll
    for (int m = 1; m <= 32; m <<= 1) s += __shfl_xor(s, m);
    if (lane == 0) Y[bid] = s;
}

// single block: /cnt + z-gate + h-gate (LDS reused) + combine
__global__ __launch_bounds__(512) void kTail(const float* __restrict__ Y,
        const float* __restrict__ cnt, const float* __restrict__ H,
        const float* __restrict__ Wz, const float* __restrict__ bz,
        const float* __restrict__ lzW, const float* __restrict__ lzb,
        const float* __restrict__ Wh, const float* __restrict__ bh,
        const float* __restrict__ lhW, const float* __restrict__ lhb,
        float* __restrict__ out) {
    __shared__ float Ws[64 * 64];
    __shared__ float lWs[128 * 64];
    __shared__ float Ys[512], Hs[512], P[512], Gz[512];
    __shared__ float cnt_s[NB];
    const int t = threadIdx.x;
    const int g = t >> 6, j = t & 63;

    const float yv = Y[t];
    if (t < NB) cnt_s[t] = fmaxf(cnt[t], 1.0f);
    Hs[t] = H[t];
    {
        const float4* W4  = reinterpret_cast<const float4*>(Wz);
        const float4* lW4 = reinterpret_cast<const float4*>(lzW);
        float4* Ws4  = reinterpret_cast<float4*>(Ws);
        float4* lWs4 = reinterpret_cast<float4*>(lWs);
        #pragma unroll
        for (int i = 0; i < 2; ++i) Ws4[t + 512 * i] = W4[t + 512 * i];
        #pragma unroll
        for (int i = 0; i < 4; ++i) lWs4[t + 512 * i] = lW4[t + 512 * i];
    }
    __syncthreads();
    Ys[t] = yv / cnt_s[g];
    __syncthreads();

    float p = bz[j];
    #pragma unroll 8
    for (int k = 0; k < 64; ++k) p += Ys[g * 64 + k] * Ws[k * 64 + j];
    P[t] = p;
    __syncthreads();
    float az = lzb[j];
    #pragma unroll 8
    for (int k = 0; k < 64; ++k)
        az += P[g * 64 + k] * lWs[k * 64 + j] + Hs[g * 64 + k] * lWs[(64 + k) * 64 + j];
    Gz[t] = 1.f / (1.f + expf(-az));
    __syncthreads();

    {
        const float4* W4  = reinterpret_cast<const float4*>(Wh);
        const float4* lW4 = reinterpret_cast<const float4*>(lhW);
        float4* Ws4  = reinterpret_cast<float4*>(Ws);
        float4* lWs4 = reinterpret_cast<float4*>(lWs);
        #pragma unroll
        for (int i = 0; i < 2; ++i) Ws4[t + 512 * i] = W4[t + 512 * i];
        #pragma unroll
        for (int i = 0; i < 4; ++i) lWs4[t + 512 * i] = lW4[t + 512 * i];
    }
    __syncthreads();

    p = bh[j];
    #pragma unroll 8
    for (int k = 0; k < 64; ++k) p += Ys[g * 64 + k] * Ws[k * 64 + j];
    P[t] = p;
    __syncthreads();
    float ah = lhb[j];
    #pragma unroll 8
    for (int k = 0; k < 64; ++k)
        ah += P[g * 64 + k] * lWs[k * 64 + j] + Hs[g * 64 + k] * lWs[(64 + k) * 64 + j];
    const float Ht = tanhf(ah);

    out[t] = Gz[t] * Hs[t] + (1.f - Gz[t]) * Ht;
}

extern "C" void kernel_launch(void* const* d_in, const int* in_sizes, int n_in,
                              void* d_out, int out_size, void* d_ws, size_t ws_size,
                              hipStream_t stream) {
    (void)in_sizes; (void)n_in; (void)out_size; (void)ws_size;

    const float* X     = (const float*)d_in[0];
    const int*   ei    = (const int*)d_in[1];
    const int*   rowp  = ei;
    const int*   colp  = ei + N_EDGES;
    const int*   batch = (const int*)d_in[2];
    const float* ew    = (const float*)d_in[3];
    const float* H     = (const float*)d_in[4];
    const float* Wz  = (const float*)d_in[5];
    const float* bz  = (const float*)d_in[6];
    const float* lzW = (const float*)d_in[7];
    const float* lzb = (const float*)d_in[8];
    // gate r (d_in[9..12]) computed-but-unused in the reference -> skipped
    const float* Wh  = (const float*)d_in[13];
    const float* bh  = (const float*)d_in[14];
    const float* lhW = (const float*)d_in[15];
    const float* lhb = (const float*)d_in[16];
    float* out = (float*)d_out;

    const long NCAP = (long)NBUCK * CAP;
    int*   cursors = (int*)d_ws;                           // 512*16 ints
    float* cntG    = (float*)(cursors + 2 * NBUCK * 16);   // 8
    float* partial = cntG + NB;                            // 256*512
    float* Yv      = partial + (long)NBUCK * 512;          // 512
    uint2* db      = (uint2*)(Yv + 512);                   // N * 8B
    uint2* rowBin  = db + N_NODES;                         // NCAP * 8B
    uint2* colBin  = rowBin + NCAP;                        // NCAP * 8B

    kInit<<<1, 512, 0, stream>>>(cursors, cntG);
    kC<<<NCHUNK, 512, 0, stream>>>(rowp, colp, ew, cursors, rowBin, colBin);
    kD_degacc<<<NBUCK, 512, 0, stream>>>(colBin, cursors, batch, db, cntG);
    kD_bucket<<<NBUCK, 512, 0, stream>>>(X, rowBin, cursors, db, partial);
    k45_reduce<<<512, 64, 0, stream>>>(partial, Yv);
    kTail<<<1, 512, 0, stream>>>(Yv, cntG, H, Wz, bz, lzW, lzb, Wh, bh, lhW, lhb, out);
}